// Round 3
// baseline (119.593 us; speedup 1.0000x reference)
//
#include <hip/hip_runtime.h>
#include <stdint.h>

#define N_IMG 32
#define P_TOT 8400
#define NCLS 80
#define NMS_PRE 1000
#define MAXOUT 100
#define SCORE_THRF 0.01f
#define NMS_THRF 0.65f
#define NBIN 16384      // 14-bit bins: exponent(8) + top-6 mantissa of descending key
#define CAND_N 2048
#define MWORDS 16       // 1000 bits -> 16 uint64 words
#define MROW 1000       // mask row count (and word-row stride)

// Level layout: p in [0,6400): 80x80 s=8 ; [6400,8000): 40x40 s=16 ; [8000,8400): 20x20 s=32

__device__ __forceinline__ float sigmoidf_(float x) { return 1.0f / (1.0f + expf(-x)); }

// ---------------- Kernel 1: scores -> sort keys ----------------
__global__ __launch_bounds__(256) void k_score(
    const float* __restrict__ cls0, const float* __restrict__ cls1, const float* __restrict__ cls2,
    const float* __restrict__ obj0, const float* __restrict__ obj1, const float* __restrict__ obj2,
    uint64_t* __restrict__ keys)
{
    int gid = blockIdx.x * blockDim.x + threadIdx.x;
    if (gid >= N_IMG * P_TOT) return;
    int n = gid / P_TOT, p = gid - n * P_TOT;

    const float* cl; const float* ob; int HW, q;
    if (p < 6400)      { cl = cls0; ob = obj0; HW = 6400; q = p; }
    else if (p < 8000) { cl = cls1; ob = obj1; HW = 1600; q = p - 6400; }
    else               { cl = cls2; ob = obj2; HW = 400;  q = p - 8000; }

    const float* cbase = cl + (size_t)n * NCLS * HW + q;
    // argmax over sigmoid(cls) (first max wins, like jnp.argmax)
    float best = -1.0f; int bc = 0;
    #pragma unroll 4
    for (int c = 0; c < NCLS; ++c) {
        float s = sigmoidf_(cbase[(size_t)c * HW]);
        if (s > best) { best = s; bc = c; }
    }
    float so = sigmoidf_(ob[(size_t)n * HW + q]);
    float sc = __fmul_rn(best, so);
    float masked = (sc >= SCORE_THRF) ? sc : -1.0f;

    // descending-order sortable key; ties broken by ascending p (lax.top_k semantics)
    uint32_t u = __float_as_uint(masked);
    uint32_t ord = (u & 0x80000000u) ? ~u : (u | 0x80000000u); // ascending order map
    uint32_t dk = ~ord;                                         // descending (valid => top bit 0)
    keys[gid] = ((uint64_t)dk << 32) | (uint32_t)((p << 8) | bc);
}

// ---------------- Kernel 2: histogram-select top-1000 + sort-2048 + decode ----------------
__global__ __launch_bounds__(1024) void k_select(
    const uint64_t* __restrict__ keys,
    const float* __restrict__ reg0, const float* __restrict__ reg1, const float* __restrict__ reg2,
    float4* __restrict__ selA, float4* __restrict__ selB, int* __restrict__ nvalid)
{
    __shared__ uint32_t hist[NBIN];       // 64 KiB
    __shared__ uint64_t cand[CAND_N];     // 16 KiB
    __shared__ uint32_t wsum[16];
    __shared__ uint32_t woff[17];
    __shared__ uint32_t s_misc[2];        // [0]=cutoff bin, [1]=cand count
    __shared__ float    fsh[17];

    int n = blockIdx.x, tid = threadIdx.x;

    for (int t = tid; t < NBIN; t += 1024) hist[t] = 0;
    for (int t = tid; t < CAND_N; t += 1024) cand[t] = ~0ull;
    if (tid == 0) { s_misc[0] = 0; s_misc[1] = 0; }
    __syncthreads();

    // histogram valid keys; cache keys in registers for the compaction pass
    uint64_t rk[9];
    #pragma unroll
    for (int it = 0; it < 9; ++it) {
        int t = tid + it * 1024;
        uint64_t k = ~0ull;
        if (t < P_TOT) {
            k = keys[(size_t)n * P_TOT + t];
            uint32_t dk = (uint32_t)(k >> 32);
            if (!(dk & 0x80000000u)) atomicAdd(&hist[dk >> 17], 1u);
        }
        rk[it] = k;
    }
    __syncthreads();

    // block scan over bins: thread i owns bins [16i, 16i+16)
    uint32_t part = 0;
    #pragma unroll
    for (int b = 0; b < 16; ++b) part += hist[tid * 16 + b];
    uint32_t inc = part;
    #pragma unroll
    for (int o = 1; o < 64; o <<= 1) {
        uint32_t v = __shfl_up(inc, o);
        if ((tid & 63) >= o) inc += v;
    }
    if ((tid & 63) == 63) wsum[tid >> 6] = inc;
    __syncthreads();
    if (tid == 0) {
        uint32_t acc = 0;
        #pragma unroll
        for (int w = 0; w < 16; ++w) { woff[w] = acc; acc += wsum[w]; }
        woff[16] = acc;
    }
    __syncthreads();
    uint32_t total = woff[16];
    uint32_t target = total < (uint32_t)NMS_PRE ? total : (uint32_t)NMS_PRE;
    uint32_t exc = woff[tid >> 6] + (inc - part);   // exclusive prefix of my chunk
    if (total > 0 && exc < target && exc + part >= target) {
        uint32_t c = exc; int b = 0;
        #pragma unroll
        for (int bb = 0; bb < 16; ++bb) {
            c += hist[tid * 16 + bb];
            if (c >= target) { b = bb; break; }
        }
        s_misc[0] = (uint32_t)(tid * 16 + b);
    }
    __syncthreads();
    uint32_t Bcut = s_misc[0];

    // compact candidates (bins <= Bcut) from the register cache
    #pragma unroll
    for (int it = 0; it < 9; ++it) {
        uint64_t k = rk[it];
        uint32_t dk = (uint32_t)(k >> 32);
        if (!(dk & 0x80000000u) && (dk >> 17) <= Bcut) {
            uint32_t slot = atomicAdd(&s_misc[1], 1u);
            if (slot < CAND_N) cand[slot] = k;
        }
    }
    __syncthreads();

    // bitonic sort 2048 (ascending key = descending score, index-tiebroken)
    for (int k = 2; k <= CAND_N; k <<= 1) {
        for (int j = k >> 1; j > 0; j >>= 1) {
            int i = ((tid & ~(j - 1)) << 1) | (tid & (j - 1));
            int ixj = i | j;
            uint64_t a = cand[i], b = cand[ixj];
            bool up = (i & k) == 0;
            if (up ? (a > b) : (a < b)) { cand[i] = b; cand[ixj] = a; }
            __syncthreads();
        }
    }

    // decode top-1000 exactly like reference (mul/add separately rounded)
    float4 bx = make_float4(0.f, 0.f, 0.f, 0.f);
    float scm = -1.0f, labf = 0.f, m = 0.f;
    if (tid < NMS_PRE) {
        uint64_t key = cand[tid];
        uint32_t dk = (uint32_t)(key >> 32);
        if (!(dk & 0x80000000u)) {
            uint32_t low = (uint32_t)key;
            int lab = (int)(low & 0xFFu);
            int p   = (int)(low >> 8);
            uint32_t ord = ~dk;
            scm = __uint_as_float(ord ^ 0x80000000u);   // valid => positive float

            const float* rg; int HW, q, W; float s;
            if (p < 6400)      { rg = reg0; HW = 6400; q = p;        W = 80; s = 8.f; }
            else if (p < 8000) { rg = reg1; HW = 1600; q = p - 6400; W = 40; s = 16.f; }
            else               { rg = reg2; HW = 400;  q = p - 8000; W = 20; s = 32.f; }

            float px = (float)(q % W) * s;   // exact
            float py = (float)(q / W) * s;   // exact
            const float* rb = rg + (size_t)n * 4 * HW + q;
            float dx = rb[0], dy = rb[HW], dw = rb[2 * HW], dh = rb[3 * HW];
            float cx = __fadd_rn(__fmul_rn(dx, s), px);
            float cy = __fadd_rn(__fmul_rn(dy, s), py);
            float hw = __fmul_rn(__fmul_rn(expf(dw), s), 0.5f);
            float hh = __fmul_rn(__fmul_rn(expf(dh), s), 0.5f);
            bx.x = __fsub_rn(cx, hw); bx.y = __fsub_rn(cy, hh);
            bx.z = __fadd_rn(cx, hw); bx.w = __fadd_rn(cy, hh);
            labf = (float)lab;
            m = fmaxf(fmaxf(fabsf(bx.x), fabsf(bx.y)), fmaxf(fabsf(bx.z), fabsf(bx.w)));
        }
    }

    // block max-reduce of |b| over the 1000 gathered boxes
    #pragma unroll
    for (int o = 32; o > 0; o >>= 1) m = fmaxf(m, __shfl_xor(m, o));
    if ((tid & 63) == 0) fsh[tid >> 6] = m;
    __syncthreads();
    if (tid == 0) {
        float g = fsh[0];
        #pragma unroll
        for (int w = 1; w < 16; ++w) g = fmaxf(g, fsh[w]);
        fsh[16] = g;
        nvalid[n] = (int)target;
    }
    __syncthreads();
    float gmax = fsh[16];

    if (tid < NMS_PRE) {
        float off = __fmul_rn(labf, __fadd_rn(gmax, 1.0f)); // lab * (max|b| + 1)
        selA[n * NMS_PRE + tid] = bx;                        // raw box (output)
        selB[n * NMS_PRE + tid] = make_float4(scm, labf, off, 0.f);
    }
}

// ---------------- Kernel 3: parallel suppression bitmask ----------------
// maskT[n][w][r] (word-transposed): bit b of word = (iou(r, 64w+b) > THR) && (64w+b > r)
__global__ __launch_bounds__(256) void k_iou(
    const float4* __restrict__ selA, const float4* __restrict__ selB,
    uint64_t* __restrict__ maskT)
{
    __shared__ float4 obx[NMS_PRE];   // offset boxes
    __shared__ float  oar[NMS_PRE];   // areas of offset boxes
    int n = blockIdx.x >> 3, part = blockIdx.x & 7;
    int tid = threadIdx.x;

    for (int t = tid; t < NMS_PRE; t += 256) {
        float4 b    = selA[n * NMS_PRE + t];
        float4 meta = selB[n * NMS_PRE + t];
        float off = meta.z;
        float x1 = __fadd_rn(b.x, off), y1 = __fadd_rn(b.y, off);
        float x2 = __fadd_rn(b.z, off), y2 = __fadd_rn(b.w, off);
        obx[t] = make_float4(x1, y1, x2, y2);
        oar[t] = __fmul_rn(__fsub_rn(x2, x1), __fsub_rn(y2, y1));
    }
    __syncthreads();

    int rbase = part * 125;
    uint64_t* M = maskT + (size_t)n * (MWORDS * MROW);
    for (int idx = tid; idx < 125 * MWORDS; idx += 256) {
        int w = idx / 125;            // word index 0..15 (wave-uniform-ish: broadcast LDS reads)
        int r = rbase + (idx - w * 125);
        if (w < (r >> 6)) continue;   // never read by the scan
        float4 bi = obx[r]; float ai = oar[r];
        uint64_t bits = 0;
        int jbase = w << 6;
        #pragma unroll 4
        for (int jj = 0; jj < 64; ++jj) {
            int j = jbase + jj;
            float4 bj = obx[j]; float aj = oar[j];
            float ltx = fmaxf(bi.x, bj.x), lty = fmaxf(bi.y, bj.y);
            float rbx = fminf(bi.z, bj.z), rby = fminf(bi.w, bj.w);
            float ww = fmaxf(__fsub_rn(rbx, ltx), 0.f);
            float hh = fmaxf(__fsub_rn(rby, lty), 0.f);
            float inter = __fmul_rn(ww, hh);
            float denom = __fadd_rn(__fsub_rn(__fadd_rn(ai, aj), inter), 1e-9f);
            bool s = (inter / denom > NMS_THRF) && (j > r);
            bits |= ((uint64_t)s) << jj;
        }
        M[w * MROW + r] = bits;
    }
}

// ---------------- Kernel 4: greedy scan over bitmask (1 wave / image) ----------------
__global__ __launch_bounds__(64) void k_scan(
    const uint64_t* __restrict__ maskT,
    const float4* __restrict__ selA, const float4* __restrict__ selB,
    const int* __restrict__ nvalid, float* __restrict__ out)
{
    __shared__ int kidx[MAXOUT];
    int n = blockIdx.x, lane = threadIdx.x;
    int V = nvalid[n];
    const uint64_t* M = maskT + (size_t)n * (MWORDS * MROW);

    int count = 0;
    for (int c = 0; c * 64 < V && count < MAXOUT; ++c) {
        int ri = c * 64 + lane;
        uint64_t wcur = M[c * MROW + (ri < MROW ? ri : MROW - 1)]; // lane's row, word c
        // suppressed-mask for this chunk from previously kept rows (uniform broadcast loads)
        uint64_t bm = 0;
        for (int m = 0; m < count; ++m) bm |= M[c * MROW + kidx[m]];
        int lim = V - c * 64; if (lim > 64) lim = 64;
        for (int b = 0; b < lim && count < MAXOUT; ++b) {
            if (!((bm >> b) & 1)) {
                if (lane == 0) kidx[count] = c * 64 + b;
                ++count;
                bm |= __shfl(wcur, b);   // row b's suppression bits for this chunk
            }
        }
    }
    __syncthreads();

    float* ob = out;                          // [32*100*4]
    float* os = out + N_IMG * MAXOUT * 4;     // [32*100]
    float* ol = os + N_IMG * MAXOUT;          // [32*100] labels as float
    for (int m = lane; m < MAXOUT; m += 64) {
        int o4 = (n * MAXOUT + m) * 4;
        if (m < count) {
            int i = kidx[m];
            float4 b    = selA[n * NMS_PRE + i];
            float4 meta = selB[n * NMS_PRE + i];
            ob[o4 + 0] = b.x; ob[o4 + 1] = b.y; ob[o4 + 2] = b.z; ob[o4 + 3] = b.w;
            os[n * MAXOUT + m] = meta.x;
            ol[n * MAXOUT + m] = meta.y;
        } else {
            ob[o4 + 0] = 0.f; ob[o4 + 1] = 0.f; ob[o4 + 2] = 0.f; ob[o4 + 3] = 0.f;
            os[n * MAXOUT + m] = 0.f;
            ol[n * MAXOUT + m] = -1.f;
        }
    }
}

extern "C" void kernel_launch(void* const* d_in, const int* in_sizes, int n_in,
                              void* d_out, int out_size, void* d_ws, size_t ws_size,
                              hipStream_t stream)
{
    const float* cls0 = (const float*)d_in[0];
    const float* cls1 = (const float*)d_in[1];
    const float* cls2 = (const float*)d_in[2];
    const float* reg0 = (const float*)d_in[3];
    const float* reg1 = (const float*)d_in[4];
    const float* reg2 = (const float*)d_in[5];
    const float* obj0 = (const float*)d_in[6];
    const float* obj1 = (const float*)d_in[7];
    const float* obj2 = (const float*)d_in[8];

    // ws layout: [0, 4MiB): keys (2.05 MB, dead after k_select) overlaid with
    // maskT (4.10 MB, written by k_iou after k_select). Then selA/selB/nvalid.
    uint64_t* keys  = (uint64_t*)d_ws;
    uint64_t* maskT = (uint64_t*)d_ws;
    float4* selA = (float4*)((char*)d_ws + (4u << 20));
    float4* selB = (float4*)((char*)d_ws + (4u << 20) + 512u * 1024u);
    int*  nvalid = (int*)  ((char*)d_ws + (4u << 20) + 1024u * 1024u);
    float* out = (float*)d_out;

    k_score<<<(N_IMG * P_TOT + 255) / 256, 256, 0, stream>>>(
        cls0, cls1, cls2, obj0, obj1, obj2, keys);
    k_select<<<N_IMG, 1024, 0, stream>>>(keys, reg0, reg1, reg2, selA, selB, nvalid);
    k_iou<<<N_IMG * 8, 256, 0, stream>>>(selA, selB, maskT);
    k_scan<<<N_IMG, 64, 0, stream>>>(maskT, selA, selB, nvalid, out);
}

// Round 4
// 115.713 us; speedup vs baseline: 1.0335x; 1.0335x over previous
//
#include <hip/hip_runtime.h>
#include <stdint.h>

#define N_IMG 32
#define P_TOT 8400
#define NCLS 80
#define NMS_PRE 1000
#define MAXOUT 100
#define SCORE_THRF 0.01f
#define NMS_THRF 0.65f
#define NBIN 16384      // 14-bit bins: exponent(8) + top-6 mantissa of descending key
#define CAND_N 2048

// Level layout: p in [0,6400): 80x80 s=8 ; [6400,8000): 40x40 s=16 ; [8000,8400): 20x20 s=32

__device__ __forceinline__ float sigmoidf_(float x) { return 1.0f / (1.0f + expf(-x)); }

// ---------------- Kernel 1: scores -> sort keys (float4-vectorized) ----------------
__global__ __launch_bounds__(256) void k_score(
    const float* __restrict__ cls0, const float* __restrict__ cls1, const float* __restrict__ cls2,
    const float* __restrict__ obj0, const float* __restrict__ obj1, const float* __restrict__ obj2,
    uint64_t* __restrict__ keys)
{
    int t = blockIdx.x * blockDim.x + threadIdx.x;
    if (t >= N_IMG * (P_TOT / 4)) return;
    int n = t / (P_TOT / 4);
    int p0 = (t - n * (P_TOT / 4)) * 4;      // 4 consecutive anchors, same level (6400/8000 are %4==0)

    const float* cl; const float* ob; int HW, q0;
    if (p0 < 6400)      { cl = cls0; ob = obj0; HW = 6400; q0 = p0; }
    else if (p0 < 8000) { cl = cls1; ob = obj1; HW = 1600; q0 = p0 - 6400; }
    else                { cl = cls2; ob = obj2; HW = 400;  q0 = p0 - 8000; }

    const float* cbase = cl + (size_t)n * NCLS * HW + q0;
    float best[4] = {-1.f, -1.f, -1.f, -1.f};
    int   bc[4]   = {0, 0, 0, 0};
    #pragma unroll 4
    for (int c = 0; c < NCLS; ++c) {
        float4 v = *reinterpret_cast<const float4*>(cbase + (size_t)c * HW);
        float s0 = sigmoidf_(v.x), s1 = sigmoidf_(v.y), s2 = sigmoidf_(v.z), s3 = sigmoidf_(v.w);
        if (s0 > best[0]) { best[0] = s0; bc[0] = c; }
        if (s1 > best[1]) { best[1] = s1; bc[1] = c; }
        if (s2 > best[2]) { best[2] = s2; bc[2] = c; }
        if (s3 > best[3]) { best[3] = s3; bc[3] = c; }
    }
    float4 ov = *reinterpret_cast<const float4*>(ob + (size_t)n * HW + q0);
    float so[4] = { sigmoidf_(ov.x), sigmoidf_(ov.y), sigmoidf_(ov.z), sigmoidf_(ov.w) };

    uint64_t k[4];
    #pragma unroll
    for (int e = 0; e < 4; ++e) {
        float sc = __fmul_rn(best[e], so[e]);
        float masked = (sc >= SCORE_THRF) ? sc : -1.0f;
        uint32_t u = __float_as_uint(masked);
        uint32_t ord = (u & 0x80000000u) ? ~u : (u | 0x80000000u);
        uint32_t dk = ~ord;                       // descending (valid => top bit 0)
        int p = p0 + e;
        k[e] = ((uint64_t)dk << 32) | (uint32_t)((p << 8) | bc[e]);
    }
    ulonglong2* dst = reinterpret_cast<ulonglong2*>(keys + (size_t)n * P_TOT + p0);
    dst[0] = make_ulonglong2(k[0], k[1]);
    dst[1] = make_ulonglong2(k[2], k[3]);
}

// ---------------- Kernel 2: histogram-select top-1000 + sort-2048 + decode ----------------
__global__ __launch_bounds__(1024) void k_select(
    const uint64_t* __restrict__ keys,
    const float* __restrict__ reg0, const float* __restrict__ reg1, const float* __restrict__ reg2,
    float4* __restrict__ selA, float4* __restrict__ selB, int* __restrict__ nvalid)
{
    __shared__ uint32_t hist[NBIN];       // 64 KiB
    __shared__ uint64_t cand[CAND_N];     // 16 KiB
    __shared__ uint32_t wsum[16];
    __shared__ uint32_t woff[17];
    __shared__ uint32_t s_misc[2];        // [0]=cutoff bin, [1]=cand count
    __shared__ float    fsh[17];

    int n = blockIdx.x, tid = threadIdx.x;

    for (int t = tid; t < NBIN; t += 1024) hist[t] = 0;
    for (int t = tid; t < CAND_N; t += 1024) cand[t] = ~0ull;
    if (tid == 0) { s_misc[0] = 0; s_misc[1] = 0; }
    __syncthreads();

    // histogram valid keys; cache keys in registers for the compaction pass
    uint64_t rk[9];
    #pragma unroll
    for (int it = 0; it < 9; ++it) {
        int t = tid + it * 1024;
        uint64_t k = ~0ull;
        if (t < P_TOT) {
            k = keys[(size_t)n * P_TOT + t];
            uint32_t dk = (uint32_t)(k >> 32);
            if (!(dk & 0x80000000u)) atomicAdd(&hist[dk >> 17], 1u);
        }
        rk[it] = k;
    }
    __syncthreads();

    // block scan over bins: thread i owns bins [16i, 16i+16)
    uint32_t part = 0;
    #pragma unroll
    for (int b = 0; b < 16; ++b) part += hist[tid * 16 + b];
    uint32_t inc = part;
    #pragma unroll
    for (int o = 1; o < 64; o <<= 1) {
        uint32_t v = __shfl_up(inc, o);
        if ((tid & 63) >= o) inc += v;
    }
    if ((tid & 63) == 63) wsum[tid >> 6] = inc;
    __syncthreads();
    if (tid == 0) {
        uint32_t acc = 0;
        #pragma unroll
        for (int w = 0; w < 16; ++w) { woff[w] = acc; acc += wsum[w]; }
        woff[16] = acc;
    }
    __syncthreads();
    uint32_t total = woff[16];
    uint32_t target = total < (uint32_t)NMS_PRE ? total : (uint32_t)NMS_PRE;
    uint32_t exc = woff[tid >> 6] + (inc - part);   // exclusive prefix of my chunk
    if (total > 0 && exc < target && exc + part >= target) {
        uint32_t c = exc; int b = 0;
        #pragma unroll
        for (int bb = 0; bb < 16; ++bb) {
            c += hist[tid * 16 + bb];
            if (c >= target) { b = bb; break; }
        }
        s_misc[0] = (uint32_t)(tid * 16 + b);
    }
    __syncthreads();
    uint32_t Bcut = s_misc[0];

    // compact candidates (bins <= Bcut) from the register cache
    #pragma unroll
    for (int it = 0; it < 9; ++it) {
        uint64_t k = rk[it];
        uint32_t dk = (uint32_t)(k >> 32);
        if (!(dk & 0x80000000u) && (dk >> 17) <= Bcut) {
            uint32_t slot = atomicAdd(&s_misc[1], 1u);
            if (slot < CAND_N) cand[slot] = k;
        }
    }
    __syncthreads();

    // bitonic sort 2048 (ascending key = descending score, index-tiebroken)
    for (int k = 2; k <= CAND_N; k <<= 1) {
        for (int j = k >> 1; j > 0; j >>= 1) {
            int i = ((tid & ~(j - 1)) << 1) | (tid & (j - 1));
            int ixj = i | j;
            uint64_t a = cand[i], b = cand[ixj];
            bool up = (i & k) == 0;
            if (up ? (a > b) : (a < b)) { cand[i] = b; cand[ixj] = a; }
            __syncthreads();
        }
    }

    // decode top-1000 exactly like reference (mul/add separately rounded)
    float4 bx = make_float4(0.f, 0.f, 0.f, 0.f);
    float scm = -1.0f, labf = 0.f, m = 0.f;
    if (tid < NMS_PRE) {
        uint64_t key = cand[tid];
        uint32_t dk = (uint32_t)(key >> 32);
        if (!(dk & 0x80000000u)) {
            uint32_t low = (uint32_t)key;
            int lab = (int)(low & 0xFFu);
            int p   = (int)(low >> 8);
            uint32_t ord = ~dk;
            scm = __uint_as_float(ord ^ 0x80000000u);   // valid => positive float

            const float* rg; int HW, q, W; float s;
            if (p < 6400)      { rg = reg0; HW = 6400; q = p;        W = 80; s = 8.f; }
            else if (p < 8000) { rg = reg1; HW = 1600; q = p - 6400; W = 40; s = 16.f; }
            else               { rg = reg2; HW = 400;  q = p - 8000; W = 20; s = 32.f; }

            float px = (float)(q % W) * s;   // exact
            float py = (float)(q / W) * s;   // exact
            const float* rb = rg + (size_t)n * 4 * HW + q;
            float dx = rb[0], dy = rb[HW], dw = rb[2 * HW], dh = rb[3 * HW];
            float cx = __fadd_rn(__fmul_rn(dx, s), px);
            float cy = __fadd_rn(__fmul_rn(dy, s), py);
            float hw = __fmul_rn(__fmul_rn(expf(dw), s), 0.5f);
            float hh = __fmul_rn(__fmul_rn(expf(dh), s), 0.5f);
            bx.x = __fsub_rn(cx, hw); bx.y = __fsub_rn(cy, hh);
            bx.z = __fadd_rn(cx, hw); bx.w = __fadd_rn(cy, hh);
            labf = (float)lab;
            m = fmaxf(fmaxf(fabsf(bx.x), fabsf(bx.y)), fmaxf(fabsf(bx.z), fabsf(bx.w)));
        }
    }

    // block max-reduce of |b| over the 1000 gathered boxes
    #pragma unroll
    for (int o = 32; o > 0; o >>= 1) m = fmaxf(m, __shfl_xor(m, o));
    if ((tid & 63) == 0) fsh[tid >> 6] = m;
    __syncthreads();
    if (tid == 0) {
        float g = fsh[0];
        #pragma unroll
        for (int w = 1; w < 16; ++w) g = fmaxf(g, fsh[w]);
        fsh[16] = g;
        nvalid[n] = (int)target;
    }
    __syncthreads();
    float gmax = fsh[16];

    if (tid < NMS_PRE) {
        float off = __fmul_rn(labf, __fadd_rn(gmax, 1.0f)); // lab * (max|b| + 1)
        selA[n * NMS_PRE + tid] = bx;                        // raw box (output)
        selB[n * NMS_PRE + tid] = make_float4(scm, labf, off, 0.f);
    }
}

// ---------------- Kernel 3: fused greedy NMS, lazy IoU (1 wave / image) ----------------
__global__ __launch_bounds__(64) void k_nms(
    const float4* __restrict__ selA, const float4* __restrict__ selB,
    const int* __restrict__ nvalid, float* __restrict__ out)
{
    __shared__ float4 obx[NMS_PRE];   // offset boxes
    __shared__ float  oar[NMS_PRE];   // areas (of offset boxes)
    __shared__ int    kidx[MAXOUT];
    int n = blockIdx.x, lane = threadIdx.x;
    int V = nvalid[n];

    for (int t = lane; t < NMS_PRE; t += 64) {
        float4 b    = selA[n * NMS_PRE + t];
        float4 meta = selB[n * NMS_PRE + t];
        float off = meta.z;
        float x1 = __fadd_rn(b.x, off), y1 = __fadd_rn(b.y, off);
        float x2 = __fadd_rn(b.z, off), y2 = __fadd_rn(b.w, off);
        obx[t] = make_float4(x1, y1, x2, y2);
        oar[t] = __fmul_rn(__fsub_rn(x2, x1), __fsub_rn(y2, y1));
    }
    __syncthreads();

    int count = 0;
    int nchunk = (V + 63) >> 6;
    for (int c = 0; c < nchunk && count < MAXOUT; ++c) {
        int jcol = (c << 6) + lane;           // this lane's column (candidate box)
        bool colv = jcol < V;
        int jsafe = colv ? jcol : 0;
        float4 bj = obx[jsafe];
        float  aj = oar[jsafe];

        // suppression of this chunk's 64 cols by previously kept rows (r < c*64 <= jcol)
        uint64_t bm = 0;
        for (int m = 0; m < count; ++m) {
            int r = kidx[m];
            float4 bi = obx[r]; float ai = oar[r];   // uniform-address broadcast reads
            float ltx = fmaxf(bi.x, bj.x), lty = fmaxf(bi.y, bj.y);
            float rbx = fminf(bi.z, bj.z), rby = fminf(bi.w, bj.w);
            float w = fmaxf(__fsub_rn(rbx, ltx), 0.f);
            float h = fmaxf(__fsub_rn(rby, lty), 0.f);
            float inter = __fmul_rn(w, h);
            float denom = __fadd_rn(__fsub_rn(__fadd_rn(ai, aj), inter), 1e-9f);
            bool sup = colv && (inter / denom > NMS_THRF);
            bm |= __ballot(sup);
        }

        // greedy over this chunk; kept row b's box comes from lane b's registers via shfl
        int lim = V - (c << 6); if (lim > 64) lim = 64;
        for (int b = 0; b < lim; ++b) {
            if ((bm >> b) & 1) continue;
            int r = (c << 6) + b;
            if (lane == 0) kidx[count] = r;
            ++count;
            float bix1 = __shfl(bj.x, b), biy1 = __shfl(bj.y, b);
            float bix2 = __shfl(bj.z, b), biy2 = __shfl(bj.w, b);
            float ai   = __shfl(aj,   b);
            float ltx = fmaxf(bix1, bj.x), lty = fmaxf(biy1, bj.y);
            float rbx = fminf(bix2, bj.z), rby = fminf(biy2, bj.w);
            float w = fmaxf(__fsub_rn(rbx, ltx), 0.f);
            float h = fmaxf(__fsub_rn(rby, lty), 0.f);
            float inter = __fmul_rn(w, h);
            float denom = __fadd_rn(__fsub_rn(__fadd_rn(ai, aj), inter), 1e-9f);
            bool sup = colv && (jcol > r) && (inter / denom > NMS_THRF);
            bm |= __ballot(sup);
            if (count >= MAXOUT) break;
        }
        __syncthreads();   // single wave: cheap; makes kidx writes visible
    }
    __syncthreads();

    float* ob = out;                          // [32*100*4]
    float* os = out + N_IMG * MAXOUT * 4;     // [32*100]
    float* ol = os + N_IMG * MAXOUT;          // [32*100] labels as float
    for (int m = lane; m < MAXOUT; m += 64) {
        int o4 = (n * MAXOUT + m) * 4;
        if (m < count) {
            int i = kidx[m];
            float4 b    = selA[n * NMS_PRE + i];
            float4 meta = selB[n * NMS_PRE + i];
            ob[o4 + 0] = b.x; ob[o4 + 1] = b.y; ob[o4 + 2] = b.z; ob[o4 + 3] = b.w;
            os[n * MAXOUT + m] = meta.x;
            ol[n * MAXOUT + m] = meta.y;
        } else {
            ob[o4 + 0] = 0.f; ob[o4 + 1] = 0.f; ob[o4 + 2] = 0.f; ob[o4 + 3] = 0.f;
            os[n * MAXOUT + m] = 0.f;
            ol[n * MAXOUT + m] = -1.f;
        }
    }
}

extern "C" void kernel_launch(void* const* d_in, const int* in_sizes, int n_in,
                              void* d_out, int out_size, void* d_ws, size_t ws_size,
                              hipStream_t stream)
{
    const float* cls0 = (const float*)d_in[0];
    const float* cls1 = (const float*)d_in[1];
    const float* cls2 = (const float*)d_in[2];
    const float* reg0 = (const float*)d_in[3];
    const float* reg1 = (const float*)d_in[4];
    const float* reg2 = (const float*)d_in[5];
    const float* obj0 = (const float*)d_in[6];
    const float* obj1 = (const float*)d_in[7];
    const float* obj2 = (const float*)d_in[8];

    uint64_t* keys = (uint64_t*)d_ws;                                   // 32*8400*8 B
    float4* selA = (float4*)((char*)d_ws + (4u << 20));
    float4* selB = (float4*)((char*)d_ws + (4u << 20) + 512u * 1024u);
    int*  nvalid = (int*)  ((char*)d_ws + (4u << 20) + 1024u * 1024u);
    float* out = (float*)d_out;

    k_score<<<(N_IMG * (P_TOT / 4) + 255) / 256, 256, 0, stream>>>(
        cls0, cls1, cls2, obj0, obj1, obj2, keys);
    k_select<<<N_IMG, 1024, 0, stream>>>(keys, reg0, reg1, reg2, selA, selB, nvalid);
    k_nms<<<N_IMG, 64, 0, stream>>>(selA, selB, nvalid, out);
}

// Round 5
// 88.678 us; speedup vs baseline: 1.3486x; 1.3049x over previous
//
#include <hip/hip_runtime.h>
#include <stdint.h>

#define N_IMG 32
#define P_TOT 8400
#define NCLS 80
#define NMS_PRE 1000
#define MAXOUT 100
#define SCORE_THRF 0.01f
#define NMS_THRF 0.65f
#define NBIN 16384      // 14-bit bins: exponent(8) + top-6 mantissa of descending key
#define CAND_N 2048

// Level layout: p in [0,6400): 80x80 s=8 ; [6400,8000): 40x40 s=16 ; [8000,8400): 20x20 s=32

__device__ __forceinline__ float sigmoidf_(float x) { return 1.0f / (1.0f + expf(-x)); }

// ---------------- Kernel 1: scores -> sort keys (class-parallel) ----------------
// Block = 256 thr = 4 waves; handles 64 consecutive anchors. Wave w covers classes
// [20w, 20w+20). Max+argmax via packed (sig_bits<<8)|(79-c) so uint64-max gives
// first-max-wins over computed sigmoids (bit-identical to jnp.argmax on sigmoid).
__global__ __launch_bounds__(256) void k_score(
    const float* __restrict__ cls0, const float* __restrict__ cls1, const float* __restrict__ cls2,
    const float* __restrict__ obj0, const float* __restrict__ obj1, const float* __restrict__ obj2,
    uint64_t* __restrict__ keys)
{
    __shared__ uint64_t part[4][64];
    int lane = threadIdx.x & 63, wid = threadIdx.x >> 6;
    int a = blockIdx.x * 64 + lane;          // global anchor id, < 268800 exactly
    int n = a / P_TOT;
    int p = a - n * P_TOT;

    const float* cl; const float* ob; int HW, q;
    if (p < 6400)      { cl = cls0; ob = obj0; HW = 6400; q = p; }
    else if (p < 8000) { cl = cls1; ob = obj1; HW = 1600; q = p - 6400; }
    else               { cl = cls2; ob = obj2; HW = 400;  q = p - 8000; }

    const float* cbase = cl + (size_t)n * NCLS * HW + q;
    uint64_t m = 0;
    int c0 = wid * 20;
    #pragma unroll
    for (int i = 0; i < 20; ++i) {
        int c = c0 + i;
        float s = sigmoidf_(cbase[(size_t)c * HW]);
        uint64_t pk = ((uint64_t)__float_as_uint(s) << 8) | (uint32_t)(79 - c);
        m = m > pk ? m : pk;    // equal sig -> higher (79-c) -> lower class wins
    }
    part[wid][lane] = m;
    __syncthreads();

    if (wid == 0) {
        uint64_t m0 = part[0][lane], m1 = part[1][lane];
        uint64_t m2 = part[2][lane], m3 = part[3][lane];
        uint64_t ma = m0 > m1 ? m0 : m1, mb = m2 > m3 ? m2 : m3;
        uint64_t mm = ma > mb ? ma : mb;
        float best = __uint_as_float((uint32_t)(mm >> 8));
        int bc = 79 - (int)(mm & 0xFFu);

        float so = sigmoidf_(ob[(size_t)n * HW + q]);
        float sc = __fmul_rn(best, so);
        float masked = (sc >= SCORE_THRF) ? sc : -1.0f;
        uint32_t u = __float_as_uint(masked);
        uint32_t ord = (u & 0x80000000u) ? ~u : (u | 0x80000000u);
        uint32_t dk = ~ord;                  // descending (valid => top bit 0)
        keys[a] = ((uint64_t)dk << 32) | (uint32_t)((p << 8) | bc);
    }
}

// ---------------- Kernel 2: top-1000 select + sort + decode + fused NMS ----------------
// hist slot permutation: B -> (B&15)*1024 + (B>>4), so the per-thread scan reads
// hist[b*1024 + tid] (lane-consecutive, conflict-free). Histogram scatter unchanged.
__device__ __forceinline__ uint32_t hslot(uint32_t B) { return ((B & 15u) << 10) | (B >> 4); }

__global__ __launch_bounds__(1024) void k_select(
    const uint64_t* __restrict__ keys,
    const float* __restrict__ reg0, const float* __restrict__ reg1, const float* __restrict__ reg2,
    float* __restrict__ out)
{
    __shared__ __align__(16) char big[NBIN * 4];   // hist (phase 1) / NMS arrays (phase 2)
    __shared__ uint64_t cand[CAND_N];              // 16 KiB
    __shared__ uint32_t wsum[16];
    __shared__ uint32_t woff[17];
    __shared__ uint32_t s_misc[2];                 // [0]=cutoff bin, [1]=cand count
    __shared__ float    fsh[17];
    __shared__ int      kidx[MAXOUT];

    uint32_t* hist = (uint32_t*)big;
    float4* s_obx = (float4*)big;                  // [1000] offset boxes   (16000 B)
    float4* s_raw = (float4*)(big + 16000);        // [1000] raw boxes      (16000 B)
    float2* s_sl  = (float2*)(big + 32000);        // [1000] score,label    ( 8000 B)
    float*  s_oar = (float*)(big + 40000);         // [1000] offset areas   ( 4000 B)

    int n = blockIdx.x, tid = threadIdx.x;

    for (int t = tid; t < NBIN; t += 1024) hist[t] = 0;
    for (int t = tid; t < CAND_N; t += 1024) cand[t] = ~0ull;
    if (tid == 0) { s_misc[0] = 0; s_misc[1] = 0; }
    __syncthreads();

    // histogram valid keys; cache keys in registers for the compaction pass
    uint64_t rk[9];
    #pragma unroll
    for (int it = 0; it < 9; ++it) {
        int t = tid + it * 1024;
        uint64_t k = ~0ull;
        if (t < P_TOT) {
            k = keys[(size_t)n * P_TOT + t];
            uint32_t dk = (uint32_t)(k >> 32);
            if (!(dk & 0x80000000u)) atomicAdd(&hist[hslot(dk >> 17)], 1u);
        }
        rk[it] = k;
    }
    __syncthreads();

    // block scan over bins: thread i owns bins [16i, 16i+16) (conflict-free reads)
    uint32_t part = 0;
    #pragma unroll
    for (int b = 0; b < 16; ++b) part += hist[(b << 10) + tid];
    uint32_t inc = part;
    #pragma unroll
    for (int o = 1; o < 64; o <<= 1) {
        uint32_t v = __shfl_up(inc, o);
        if ((tid & 63) >= o) inc += v;
    }
    if ((tid & 63) == 63) wsum[tid >> 6] = inc;
    __syncthreads();
    if (tid == 0) {
        uint32_t acc = 0;
        #pragma unroll
        for (int w = 0; w < 16; ++w) { woff[w] = acc; acc += wsum[w]; }
        woff[16] = acc;
    }
    __syncthreads();
    uint32_t total = woff[16];
    uint32_t target = total < (uint32_t)NMS_PRE ? total : (uint32_t)NMS_PRE;
    uint32_t exc = woff[tid >> 6] + (inc - part);   // exclusive prefix of my chunk
    if (total > 0 && exc < target && exc + part >= target) {
        uint32_t c = exc; int b = 0;
        #pragma unroll
        for (int bb = 0; bb < 16; ++bb) {
            c += hist[(bb << 10) + tid];
            if (c >= target) { b = bb; break; }
        }
        s_misc[0] = (uint32_t)(tid * 16 + b);
    }
    __syncthreads();
    uint32_t Bcut = s_misc[0];

    // compact candidates (bins <= Bcut) from the register cache
    #pragma unroll
    for (int it = 0; it < 9; ++it) {
        uint64_t k = rk[it];
        uint32_t dk = (uint32_t)(k >> 32);
        if (!(dk & 0x80000000u) && (dk >> 17) <= Bcut) {
            uint32_t slot = atomicAdd(&s_misc[1], 1u);
            if (slot < CAND_N) cand[slot] = k;
        }
    }
    __syncthreads();

    // bitonic sort 2048 (ascending key = descending score, index-tiebroken)
    for (int k = 2; k <= CAND_N; k <<= 1) {
        for (int j = k >> 1; j > 0; j >>= 1) {
            int i = ((tid & ~(j - 1)) << 1) | (tid & (j - 1));
            int ixj = i | j;
            uint64_t a = cand[i], b = cand[ixj];
            bool up = (i & k) == 0;
            if (up ? (a > b) : (a < b)) { cand[i] = b; cand[ixj] = a; }
            __syncthreads();
        }
    }

    // decode top-1000 exactly like reference (mul/add separately rounded)
    float4 bx = make_float4(0.f, 0.f, 0.f, 0.f);
    float scm = -1.0f, labf = 0.f, m = 0.f;
    if (tid < NMS_PRE) {
        uint64_t key = cand[tid];
        uint32_t dk = (uint32_t)(key >> 32);
        if (!(dk & 0x80000000u)) {
            uint32_t low = (uint32_t)key;
            int lab = (int)(low & 0xFFu);
            int p   = (int)(low >> 8);
            uint32_t ord = ~dk;
            scm = __uint_as_float(ord ^ 0x80000000u);   // valid => positive float

            const float* rg; int HW, q, W; float s;
            if (p < 6400)      { rg = reg0; HW = 6400; q = p;        W = 80; s = 8.f; }
            else if (p < 8000) { rg = reg1; HW = 1600; q = p - 6400; W = 40; s = 16.f; }
            else               { rg = reg2; HW = 400;  q = p - 8000; W = 20; s = 32.f; }

            float px = (float)(q % W) * s;   // exact
            float py = (float)(q / W) * s;   // exact
            const float* rb = rg + (size_t)n * 4 * HW + q;
            float dx = rb[0], dy = rb[HW], dw = rb[2 * HW], dh = rb[3 * HW];
            float cx = __fadd_rn(__fmul_rn(dx, s), px);
            float cy = __fadd_rn(__fmul_rn(dy, s), py);
            float hw = __fmul_rn(__fmul_rn(expf(dw), s), 0.5f);
            float hh = __fmul_rn(__fmul_rn(expf(dh), s), 0.5f);
            bx.x = __fsub_rn(cx, hw); bx.y = __fsub_rn(cy, hh);
            bx.z = __fadd_rn(cx, hw); bx.w = __fadd_rn(cy, hh);
            labf = (float)lab;
            m = fmaxf(fmaxf(fabsf(bx.x), fabsf(bx.y)), fmaxf(fabsf(bx.z), fabsf(bx.w)));
        }
    }

    // block max-reduce of |b| over the 1000 gathered boxes
    #pragma unroll
    for (int o = 32; o > 0; o >>= 1) m = fmaxf(m, __shfl_xor(m, o));
    if ((tid & 63) == 0) fsh[tid >> 6] = m;
    __syncthreads();            // also: last hist read was before the sort barriers
    if (tid == 0) {
        float g = fsh[0];
        #pragma unroll
        for (int w = 1; w < 16; ++w) g = fmaxf(g, fsh[w]);
        fsh[16] = g;
    }
    __syncthreads();
    float gmax = fsh[16];

    // stage NMS arrays into LDS (overlays dead hist region)
    if (tid < NMS_PRE) {
        float off = __fmul_rn(labf, __fadd_rn(gmax, 1.0f)); // lab * (max|b| + 1)
        float x1 = __fadd_rn(bx.x, off), y1 = __fadd_rn(bx.y, off);
        float x2 = __fadd_rn(bx.z, off), y2 = __fadd_rn(bx.w, off);
        s_obx[tid] = make_float4(x1, y1, x2, y2);
        s_oar[tid] = __fmul_rn(__fsub_rn(x2, x1), __fsub_rn(y2, y1));
        s_raw[tid] = bx;
        s_sl[tid]  = make_float2(scm, labf);
    }
    __syncthreads();
    if (tid >= 64) return;      // wave 0 finishes alone; no barriers below

    // ---- greedy NMS, lazy IoU (wave 0) ----
    int lane = tid;
    int V = (int)target;
    int count = 0;
    int nchunk = (V + 63) >> 6;
    for (int c = 0; c < nchunk && count < MAXOUT; ++c) {
        int jcol = (c << 6) + lane;
        bool colv = jcol < V;
        int jsafe = colv ? jcol : 0;
        float4 bj = s_obx[jsafe];
        float  aj = s_oar[jsafe];

        // suppression of this chunk's 64 cols by previously kept rows
        uint64_t bm = 0;
        for (int mm = 0; mm < count; ++mm) {
            int r = kidx[mm];
            float4 bi = s_obx[r]; float ai = s_oar[r];   // broadcast reads
            float ltx = fmaxf(bi.x, bj.x), lty = fmaxf(bi.y, bj.y);
            float rbx = fminf(bi.z, bj.z), rby = fminf(bi.w, bj.w);
            float w = fmaxf(__fsub_rn(rbx, ltx), 0.f);
            float h = fmaxf(__fsub_rn(rby, lty), 0.f);
            float inter = __fmul_rn(w, h);
            float denom = __fadd_rn(__fsub_rn(__fadd_rn(ai, aj), inter), 1e-9f);
            bool sup = colv && (inter / denom > NMS_THRF);
            bm |= __ballot(sup);
        }

        // greedy over this chunk; kept row b's box comes from lane b via shfl
        int lim = V - (c << 6); if (lim > 64) lim = 64;
        for (int b = 0; b < lim; ++b) {
            if ((bm >> b) & 1) continue;
            int r = (c << 6) + b;
            if (lane == 0) kidx[count] = r;
            ++count;
            float bix1 = __shfl(bj.x, b), biy1 = __shfl(bj.y, b);
            float bix2 = __shfl(bj.z, b), biy2 = __shfl(bj.w, b);
            float ai   = __shfl(aj,   b);
            float ltx = fmaxf(bix1, bj.x), lty = fmaxf(biy1, bj.y);
            float rbx = fminf(bix2, bj.z), rby = fminf(biy2, bj.w);
            float w = fmaxf(__fsub_rn(rbx, ltx), 0.f);
            float h = fmaxf(__fsub_rn(rby, lty), 0.f);
            float inter = __fmul_rn(w, h);
            float denom = __fadd_rn(__fsub_rn(__fadd_rn(ai, aj), inter), 1e-9f);
            bool sup = colv && (jcol > r) && (inter / denom > NMS_THRF);
            bm |= __ballot(sup);
            if (count >= MAXOUT) break;
        }
    }

    float* ob = out;                          // [32*100*4]
    float* os = out + N_IMG * MAXOUT * 4;     // [32*100]
    float* ol = os + N_IMG * MAXOUT;          // [32*100] labels as float
    for (int mi = lane; mi < MAXOUT; mi += 64) {
        int o4 = (n * MAXOUT + mi) * 4;
        if (mi < count) {
            int i = kidx[mi];
            float4 b  = s_raw[i];
            float2 sl = s_sl[i];
            ob[o4 + 0] = b.x; ob[o4 + 1] = b.y; ob[o4 + 2] = b.z; ob[o4 + 3] = b.w;
            os[n * MAXOUT + mi] = sl.x;
            ol[n * MAXOUT + mi] = sl.y;
        } else {
            ob[o4 + 0] = 0.f; ob[o4 + 1] = 0.f; ob[o4 + 2] = 0.f; ob[o4 + 3] = 0.f;
            os[n * MAXOUT + mi] = 0.f;
            ol[n * MAXOUT + mi] = -1.f;
        }
    }
}

extern "C" void kernel_launch(void* const* d_in, const int* in_sizes, int n_in,
                              void* d_out, int out_size, void* d_ws, size_t ws_size,
                              hipStream_t stream)
{
    const float* cls0 = (const float*)d_in[0];
    const float* cls1 = (const float*)d_in[1];
    const float* cls2 = (const float*)d_in[2];
    const float* reg0 = (const float*)d_in[3];
    const float* reg1 = (const float*)d_in[4];
    const float* reg2 = (const float*)d_in[5];
    const float* obj0 = (const float*)d_in[6];
    const float* obj1 = (const float*)d_in[7];
    const float* obj2 = (const float*)d_in[8];

    uint64_t* keys = (uint64_t*)d_ws;     // 32*8400*8 B = 2.1 MB
    float* out = (float*)d_out;

    k_score<<<(N_IMG * P_TOT) / 64, 256, 0, stream>>>(
        cls0, cls1, cls2, obj0, obj1, obj2, keys);
    k_select<<<N_IMG, 1024, 0, stream>>>(keys, reg0, reg1, reg2, out);
}

// Round 6
// 76.218 us; speedup vs baseline: 1.5691x; 1.1635x over previous
//
#include <hip/hip_runtime.h>
#include <stdint.h>

#define N_IMG 32
#define P_TOT 8400
#define NCLS 80
#define NMS_PRE 1000
#define MAXOUT 100
#define SCORE_THRF 0.01f
#define NMS_THRF 0.65f
#define CAND_N 2048
#define NB 512          // histogram bins over dk>>17
#define BINBASE 8192    // valid masked scores [0.01,1.0] -> dk>>17 in [8255,8686] strictly inside [8192,8704)

// Level layout: p in [0,6400): 80x80 s=8 ; [6400,8000): 40x40 s=16 ; [8000,8400): 20x20 s=32

__device__ __forceinline__ float sigmoidf_(float x) { return 1.0f / (1.0f + expf(-x)); }

// ---------------- Kernel 1: scores -> sort keys (class-parallel) ----------------
__global__ __launch_bounds__(256) void k_score(
    const float* __restrict__ cls0, const float* __restrict__ cls1, const float* __restrict__ cls2,
    const float* __restrict__ obj0, const float* __restrict__ obj1, const float* __restrict__ obj2,
    uint64_t* __restrict__ keys)
{
    __shared__ uint64_t part[4][64];
    int lane = threadIdx.x & 63, wid = threadIdx.x >> 6;
    int a = blockIdx.x * 64 + lane;          // global anchor id, < 268800 exactly
    int n = a / P_TOT;
    int p = a - n * P_TOT;

    const float* cl; const float* ob; int HW, q;
    if (p < 6400)      { cl = cls0; ob = obj0; HW = 6400; q = p; }
    else if (p < 8000) { cl = cls1; ob = obj1; HW = 1600; q = p - 6400; }
    else               { cl = cls2; ob = obj2; HW = 400;  q = p - 8000; }

    const float* cbase = cl + (size_t)n * NCLS * HW + q;
    uint64_t m = 0;
    int c0 = wid * 20;
    #pragma unroll
    for (int i = 0; i < 20; ++i) {
        int c = c0 + i;
        float s = sigmoidf_(cbase[(size_t)c * HW]);
        uint64_t pk = ((uint64_t)__float_as_uint(s) << 8) | (uint32_t)(79 - c);
        m = m > pk ? m : pk;    // equal sig -> higher (79-c) -> lower class wins
    }
    part[wid][lane] = m;
    __syncthreads();

    if (wid == 0) {
        uint64_t m0 = part[0][lane], m1 = part[1][lane];
        uint64_t m2 = part[2][lane], m3 = part[3][lane];
        uint64_t ma = m0 > m1 ? m0 : m1, mb = m2 > m3 ? m2 : m3;
        uint64_t mm = ma > mb ? ma : mb;
        float best = __uint_as_float((uint32_t)(mm >> 8));
        int bc = 79 - (int)(mm & 0xFFu);

        float so = sigmoidf_(ob[(size_t)n * HW + q]);
        float sc = __fmul_rn(best, so);
        float masked = (sc >= SCORE_THRF) ? sc : -1.0f;
        uint32_t u = __float_as_uint(masked);
        uint32_t ord = (u & 0x80000000u) ? ~u : (u | 0x80000000u);
        uint32_t dk = ~ord;                  // descending (valid => top bit 0)
        keys[a] = ((uint64_t)dk << 32) | (uint32_t)((p << 8) | bc);
    }
}

// ---------------- Kernel 2: counting-sort select + decode + fused NMS ----------------
__global__ __launch_bounds__(1024) void k_select(
    const uint64_t* __restrict__ keys,
    const float* __restrict__ reg0, const float* __restrict__ reg1, const float* __restrict__ reg2,
    float* __restrict__ out)
{
    __shared__ __align__(16) char big[44032];      // phase1: hist/base/fill/grouped; phase2: NMS arrays
    __shared__ uint64_t cand[CAND_N];              // rank-ordered keys (16 KiB)
    __shared__ float    fsh[17];
    __shared__ int      s_misc[2];                 // [0]=Bcut, [1]=target(V)
    __shared__ int      kidx[MAXOUT];

    // phase-1 overlays
    uint32_t* hist    = (uint32_t*)big;            //  512*4
    uint32_t* base    = (uint32_t*)(big + 2048);   //  512*4
    uint32_t* fill    = (uint32_t*)(big + 4096);   //  512*4
    uint64_t* grouped = (uint64_t*)(big + 8192);   // 2048*8 (ends at 24576)
    // phase-2 overlays
    float4* s_obx = (float4*)big;                  // [1000] offset boxes   (16000 B)
    float4* s_raw = (float4*)(big + 16000);        // [1000] raw boxes      (16000 B)
    float2* s_sl  = (float2*)(big + 32000);        // [1000] score,label    ( 8000 B)
    float*  s_oar = (float*)(big + 40000);         // [1000] offset areas   ( 4000 B)

    int n = blockIdx.x, tid = threadIdx.x;

    if (tid < NB) { hist[tid] = 0; fill[tid] = 0; }
    for (int t = tid; t < CAND_N; t += 1024) cand[t] = ~0ull;
    __syncthreads();

    // histogram valid keys; cache keys in registers for the scatter pass
    uint64_t rk[9];
    #pragma unroll
    for (int it = 0; it < 9; ++it) {
        int t = tid + it * 1024;
        uint64_t k = ~0ull;
        if (t < P_TOT) {
            k = keys[(size_t)n * P_TOT + t];
            uint32_t dk = (uint32_t)(k >> 32);
            if (!(dk & 0x80000000u)) atomicAdd(&hist[(dk >> 17) - BINBASE], 1u);
        }
        rk[it] = k;
    }
    __syncthreads();

    // wave-0 prefix over 512 bins: per-bin exclusive base, total, cutoff bin
    if (tid < 64) {
        uint32_t c[8]; uint32_t s = 0;
        #pragma unroll
        for (int i = 0; i < 8; ++i) { c[i] = hist[tid * 8 + i]; s += c[i]; }
        uint32_t inc = s;
        #pragma unroll
        for (int o = 1; o < 64; o <<= 1) {
            uint32_t v = __shfl_up(inc, o);
            if (tid >= o) inc += v;
        }
        uint32_t excl = inc - s;
        uint32_t b = excl;
        #pragma unroll
        for (int i = 0; i < 8; ++i) { base[tid * 8 + i] = b; b += c[i]; }
        uint32_t total = __shfl(inc, 63);
        uint32_t target = total < (uint32_t)NMS_PRE ? total : (uint32_t)NMS_PRE;
        uint32_t cum = excl; int found = 0x7fffffff;
        #pragma unroll
        for (int i = 0; i < 8; ++i) {
            cum += c[i];
            if (found == 0x7fffffff && cum >= target && target > 0) found = tid * 8 + i;
        }
        #pragma unroll
        for (int o = 32; o > 0; o >>= 1) { int f = __shfl_xor(found, o); found = f < found ? f : found; }
        if (tid == 0) { s_misc[0] = (total > 0) ? found : -1; s_misc[1] = (int)target; }
    }
    __syncthreads();
    int Bcut = s_misc[0];
    int V    = s_misc[1];

    // scatter candidates (bins <= Bcut) into bin-grouped order
    #pragma unroll
    for (int it = 0; it < 9; ++it) {
        uint64_t k = rk[it];
        uint32_t dk = (uint32_t)(k >> 32);
        if (!(dk & 0x80000000u)) {
            int bin = (int)((dk >> 17) - BINBASE);
            if (bin <= Bcut) {
                uint32_t pos = base[bin] + atomicAdd(&fill[bin], 1u);
                if (pos < CAND_N) grouped[pos] = k;
            }
        }
    }
    __syncthreads();

    // exact rank within bin (keys unique -> total order identical to full sort)
    int ccnt = 0;
    if (Bcut >= 0) {
        uint32_t cc = base[Bcut] + hist[Bcut];
        ccnt = cc < (uint32_t)CAND_N ? (int)cc : CAND_N;
    }
    for (int s = tid; s < ccnt; s += 1024) {
        uint64_t k = grouped[s];
        uint32_t dk = (uint32_t)(k >> 32);
        int bin = (int)((dk >> 17) - BINBASE);
        uint32_t b0 = base[bin];
        uint32_t e0 = b0 + hist[bin]; if (e0 > (uint32_t)CAND_N) e0 = CAND_N;
        uint32_t r = b0;
        for (uint32_t t = b0; t < e0; ++t) r += (grouped[t] < k) ? 1u : 0u;
        if (r < (uint32_t)CAND_N) cand[r] = k;
    }
    __syncthreads();

    // decode top-1000 exactly like reference (mul/add separately rounded)
    float4 bx = make_float4(0.f, 0.f, 0.f, 0.f);
    float scm = -1.0f, labf = 0.f, m = 0.f;
    if (tid < NMS_PRE) {
        uint64_t key = cand[tid];
        uint32_t dk = (uint32_t)(key >> 32);
        if (!(dk & 0x80000000u)) {
            uint32_t low = (uint32_t)key;
            int lab = (int)(low & 0xFFu);
            int p   = (int)(low >> 8);
            uint32_t ord = ~dk;
            scm = __uint_as_float(ord ^ 0x80000000u);   // valid => positive float

            const float* rg; int HW, q, W; float s;
            if (p < 6400)      { rg = reg0; HW = 6400; q = p;        W = 80; s = 8.f; }
            else if (p < 8000) { rg = reg1; HW = 1600; q = p - 6400; W = 40; s = 16.f; }
            else               { rg = reg2; HW = 400;  q = p - 8000; W = 20; s = 32.f; }

            float px = (float)(q % W) * s;   // exact
            float py = (float)(q / W) * s;   // exact
            const float* rb = rg + (size_t)n * 4 * HW + q;
            float dx = rb[0], dy = rb[HW], dw = rb[2 * HW], dh = rb[3 * HW];
            float cx = __fadd_rn(__fmul_rn(dx, s), px);
            float cy = __fadd_rn(__fmul_rn(dy, s), py);
            float hw = __fmul_rn(__fmul_rn(expf(dw), s), 0.5f);
            float hh = __fmul_rn(__fmul_rn(expf(dh), s), 0.5f);
            bx.x = __fsub_rn(cx, hw); bx.y = __fsub_rn(cy, hh);
            bx.z = __fadd_rn(cx, hw); bx.w = __fadd_rn(cy, hh);
            labf = (float)lab;
            m = fmaxf(fmaxf(fabsf(bx.x), fabsf(bx.y)), fmaxf(fabsf(bx.z), fabsf(bx.w)));
        }
    }

    // block max-reduce of |b| over the 1000 gathered boxes
    #pragma unroll
    for (int o = 32; o > 0; o >>= 1) m = fmaxf(m, __shfl_xor(m, o));
    if ((tid & 63) == 0) fsh[tid >> 6] = m;
    __syncthreads();
    if (tid == 0) {
        float g = fsh[0];
        #pragma unroll
        for (int w = 1; w < 16; ++w) g = fmaxf(g, fsh[w]);
        fsh[16] = g;
    }
    __syncthreads();
    float gmax = fsh[16];

    // stage NMS arrays into LDS (overlays dead phase-1 region)
    if (tid < NMS_PRE) {
        float off = __fmul_rn(labf, __fadd_rn(gmax, 1.0f)); // lab * (max|b| + 1)
        float x1 = __fadd_rn(bx.x, off), y1 = __fadd_rn(bx.y, off);
        float x2 = __fadd_rn(bx.z, off), y2 = __fadd_rn(bx.w, off);
        s_obx[tid] = make_float4(x1, y1, x2, y2);
        s_oar[tid] = __fmul_rn(__fsub_rn(x2, x1), __fsub_rn(y2, y1));
        s_raw[tid] = bx;
        s_sl[tid]  = make_float2(scm, labf);
    }
    __syncthreads();
    if (tid >= 64) return;      // wave 0 finishes alone

    // ---- greedy NMS: lanes = kept boxes, candidates scanned serially ----
    int lane = tid;
    int count = 0;
    float4 g = make_float4(0.f, 0.f, 0.f, 0.f);
    float  gar = 0.f;
    float k1x1 = 0.f, k1y1 = 0.f, k1x2 = 0.f, k1y2 = 0.f, k1a = 0.f;  // kept[lane]
    float k2x1 = 0.f, k2y1 = 0.f, k2x2 = 0.f, k2y2 = 0.f, k2a = 0.f;  // kept[lane+64]

    for (int i = 0; i < V && count < MAXOUT; ++i) {
        if ((i & 63) == 0) {
            int idx = i + lane; if (idx > V - 1) idx = V - 1;
            g = s_obx[idx]; gar = s_oar[idx];
        }
        int src = i & 63;
        float bx1 = __shfl(g.x, src), by1 = __shfl(g.y, src);
        float bx2 = __shfl(g.z, src), by2 = __shfl(g.w, src);
        float ba  = __shfl(gar,  src);

        bool sup = false;
        int c1 = count < 64 ? count : 64;
        if (lane < c1) {
            float ltx = fmaxf(k1x1, bx1), lty = fmaxf(k1y1, by1);
            float rbx = fminf(k1x2, bx2), rby = fminf(k1y2, by2);
            float w = fmaxf(__fsub_rn(rbx, ltx), 0.f);
            float h = fmaxf(__fsub_rn(rby, lty), 0.f);
            float inter = __fmul_rn(w, h);
            float denom = __fadd_rn(__fsub_rn(__fadd_rn(k1a, ba), inter), 1e-9f);
            sup = (inter / denom > NMS_THRF);
        }
        if (count > 64 && lane < count - 64) {
            float ltx = fmaxf(k2x1, bx1), lty = fmaxf(k2y1, by1);
            float rbx = fminf(k2x2, bx2), rby = fminf(k2y2, by2);
            float w = fmaxf(__fsub_rn(rbx, ltx), 0.f);
            float h = fmaxf(__fsub_rn(rby, lty), 0.f);
            float inter = __fmul_rn(w, h);
            float denom = __fadd_rn(__fsub_rn(__fadd_rn(k2a, ba), inter), 1e-9f);
            sup = sup || (inter / denom > NMS_THRF);
        }
        if (__ballot(sup) == 0ull) {
            if (lane == count)      { k1x1 = bx1; k1y1 = by1; k1x2 = bx2; k1y2 = by2; k1a = ba; }
            if (lane + 64 == count) { k2x1 = bx1; k2y1 = by1; k2x2 = bx2; k2y2 = by2; k2a = ba; }
            if (lane == 0) kidx[count] = i;
            ++count;
        }
    }

    float* ob = out;                          // [32*100*4]
    float* os = out + N_IMG * MAXOUT * 4;     // [32*100]
    float* ol = os + N_IMG * MAXOUT;          // [32*100] labels as float
    for (int mi = lane; mi < MAXOUT; mi += 64) {
        int o4 = (n * MAXOUT + mi) * 4;
        if (mi < count) {
            int i = kidx[mi];
            float4 b  = s_raw[i];
            float2 sl = s_sl[i];
            ob[o4 + 0] = b.x; ob[o4 + 1] = b.y; ob[o4 + 2] = b.z; ob[o4 + 3] = b.w;
            os[n * MAXOUT + mi] = sl.x;
            ol[n * MAXOUT + mi] = sl.y;
        } else {
            ob[o4 + 0] = 0.f; ob[o4 + 1] = 0.f; ob[o4 + 2] = 0.f; ob[o4 + 3] = 0.f;
            os[n * MAXOUT + mi] = 0.f;
            ol[n * MAXOUT + mi] = -1.f;
        }
    }
}

extern "C" void kernel_launch(void* const* d_in, const int* in_sizes, int n_in,
                              void* d_out, int out_size, void* d_ws, size_t ws_size,
                              hipStream_t stream)
{
    const float* cls0 = (const float*)d_in[0];
    const float* cls1 = (const float*)d_in[1];
    const float* cls2 = (const float*)d_in[2];
    const float* reg0 = (const float*)d_in[3];
    const float* reg1 = (const float*)d_in[4];
    const float* reg2 = (const float*)d_in[5];
    const float* obj0 = (const float*)d_in[6];
    const float* obj1 = (const float*)d_in[7];
    const float* obj2 = (const float*)d_in[8];

    uint64_t* keys = (uint64_t*)d_ws;     // 32*8400*8 B = 2.1 MB
    float* out = (float*)d_out;

    k_score<<<(N_IMG * P_TOT) / 64, 256, 0, stream>>>(
        cls0, cls1, cls2, obj0, obj1, obj2, keys);
    k_select<<<N_IMG, 1024, 0, stream>>>(keys, reg0, reg1, reg2, out);
}